// Round 9
// baseline (708.614 us; speedup 1.0000x reference)
//
#include <hip/hip_runtime.h>
#include <hip/hip_fp16.h>
#include <hip/hip_cooperative_groups.h>

namespace cg = cooperative_groups;

// LiftSplatBEV: B=2, N=6, C=64, HF=112, WF=200, D=64, BEV 200x200
#define BB   2
#define NN   6
#define CCH  64
#define HFE  112
#define WFE  200
#define DDE  64
#define HWF  (HFE*WFE)      // 22400 feature pixels (= 350*64)
#define BEVH 200
#define BEVW 200
#define HWB  (BEVH*BEVW)    // 40000 BEV cells
#define NBINS (BB*HWB)      // 80000 (b,cell) bins
#define NBINS_PAD 81920     // 320*256
#define NSCANB (NBINS_PAD/256)  // 320
#define MAXENT1 (BB*NN*HWF)     // 268,800 max entries (ONE per valid pixel)
#define NCHUNK1 (MAXENT1/64)    // 4200 64-entry chunks
#define ACC_ELEMS ((size_t)BB*HWB*CCH)   // channel-last [b*HWB+cell][c]

__device__ __forceinline__ float4 f4max(float4 a, float4 b) {
    return make_float4(fmaxf(a.x,b.x), fmaxf(a.y,b.y), fmaxf(a.z,b.z), fmaxf(a.w,b.w));
}

// pack 8 floats -> 8 halves (16B)
__device__ __forceinline__ uint4 pack8h(float4 a, float4 b) {
    __half2 h0 = __float22half2_rn(make_float2(a.x, a.y));
    __half2 h1 = __float22half2_rn(make_float2(a.z, a.w));
    __half2 h2 = __float22half2_rn(make_float2(b.x, b.y));
    __half2 h3 = __float22half2_rn(make_float2(b.z, b.w));
    uint4 u;
    u.x = *(unsigned*)&h0; u.y = *(unsigned*)&h1;
    u.z = *(unsigned*)&h2; u.w = *(unsigned*)&h3;
    return u;
}

// ---------------- shared geometry (bug-faithful to reference) ----------------
struct Geo {
    int valid;
    int c00;
    float w00, w10, w01, w11;
};

__device__ __forceinline__ Geo geo_compute(int bn, int p,
    const float* __restrict__ I_inv, const float* __restrict__ E_inv,
    const float* __restrict__ Vm)
{
    Geo g; g.valid = 0; g.c00 = -1;
    g.w00 = g.w10 = g.w01 = g.w11 = 0.f;
    // bug-faithful w-outer flatten: u = p/112, v = p%112
    const float u = (float)(p / HFE);
    const float v = (float)(p % HFE);
    const float* Ii = I_inv + bn * 9;
    const float* Ei = E_inv + bn * 16;
    float cx = Ii[0]*u + Ii[1]*v + Ii[2];
    float cy = Ii[3]*u + Ii[4]*v + Ii[5];
    float cz = Ii[6]*u + Ii[7]*v + Ii[8];
    float tx = Ei[3], ty = Ei[7], tz = Ei[11];
    float dx = Ei[0]*cx + Ei[1]*cy + Ei[2] *cz + tx;   // includes translation (bug-faithful)
    float dy = Ei[4]*cx + Ei[5]*cy + Ei[6] *cz + ty;
    float dz = Ei[8]*cx + Ei[9]*cy + Ei[10]*cz + tz;
    float s  = -tz / fmaxf(dz, 1e-6f);
    float ex = tx + dx * s;
    float ey = ty + dy * s;
    float prx = Vm[0]*ex + Vm[1]*ey + Vm[2];
    float pry = Vm[3]*ex + Vm[4]*ey + Vm[5];
    float prz = Vm[6]*ex + Vm[7]*ey + Vm[8];
    float den = fmaxf(prz, 1e-7f);
    float bx = prx / den, by = pry / den;
    // bug-faithful gx->px roundtrip, same association order as reference
    float gx = bx / (float)(BEVW-1) * 2.0f - 1.0f;
    float gy = by / (float)(BEVH-1) * 2.0f - 1.0f;
    float px = (gx + 1.0f) * (float)(BEVW-1) / 2.0f;
    float py = (gy + 1.0f) * (float)(BEVH-1) / 2.0f;
    float x0f = fminf(fmaxf(floorf(px), 0.0f), (float)(BEVW-1));
    float y0f = fminf(fmaxf(floorf(py), 0.0f), (float)(BEVH-1));
    float x1f = fminf(x0f + 1.0f, (float)(BEVW-1));
    float y1f = fminf(y0f + 1.0f, (float)(BEVH-1));
    // far-edge-degenerate slots cancel exactly in the fp64 np reference: skip
    if (x0f == x1f || y0f == y1f) return g;
    float wx0 = x1f - px, wx1 = px - x0f;
    float wy0 = y1f - py, wy1 = py - y0f;
    int x0 = (int)x0f, y0 = (int)y0f;
    g.c00 = y0*BEVW + x0;
    g.w00 = wx0*wy0;  g.w10 = wx1*wy0;
    g.w01 = wx0*wy1;  g.w11 = wx1*wy1;
    // for valid pixels x1=x0+1, y1=y0+1 => corners = c00 + {0,1,200,201}
    g.valid = 1;
    return g;
}

// Wave-run aggregation: consecutive lanes holding the same cell form a run.
__device__ __forceinline__ void run_info(int cell, int lane,
                                         bool& leader, int& runlen, int& leadlane)
{
    int prev = __shfl_up(cell, 1);
    bool change = (lane == 0) || (cell != prev);
    unsigned long long bal = __ballot(change);
    unsigned long long below = bal & (~0ull >> (63 - lane));
    leadlane = 63 - __builtin_clzll(below);
    unsigned long long above = (lane == 63) ? 0ull : (bal >> (lane + 1));
    int next = (above == 0ull) ? 64 : (lane + 1 + __builtin_ffsll((long long)above) - 1);
    runlen = next - lane;
    leader = change && (cell >= 0);
}

__device__ __forceinline__ unsigned pack2w(float a, float b) {
    unsigned ua = __float2uint_rn(a * 65535.0f);
    unsigned ub = __float2uint_rn(b * 65535.0f);
    return ua | (ub << 16);
}

// ====================== cooperative mega-kernel (all phases) ======================
// Phases (each body byte-identical to its measured standalone kernel, grid-strided):
//   0 zero acc+counts | 1 prep (transpose fp16 + conf + c00 hist) | 2a scan1 |
//   2b scan3 | 3 place | 4 gather | 5 finalize.  6 grid.sync()s, no early returns.
// LDS: 17,408B union (prep per-wave tiles / scan tmp / finalize tile).
__global__ __launch_bounds__(256) void mega_kernel(
    const float* __restrict__ feat, const float* __restrict__ depth,
    const float* __restrict__ I_inv, const float* __restrict__ E_inv,
    const float* __restrict__ Vm,
    __half* __restrict__ feat_t, float* __restrict__ conf,
    int* __restrict__ counts, int* __restrict__ offsets, int* __restrict__ cursor,
    int* __restrict__ bsum, uint4* __restrict__ entries,
    float* __restrict__ acc, float* __restrict__ out)
{
    cg::grid_group grid = cg::this_grid();
    __shared__ __align__(16) unsigned char smem[17408];

    const int tid  = threadIdx.x;
    const int lane = tid & 63, wv = tid >> 6;
    const int bid  = blockIdx.x, nb = gridDim.x;

    // ---- phase 0: zero acc + counts ----
    {
        float4* a4 = (float4*)acc;
        const int n4 = (int)(ACC_ELEMS / 4);               // 1,280,000
        for (int i = bid * 256 + tid; i < n4; i += nb * 256)
            a4[i] = make_float4(0.f, 0.f, 0.f, 0.f);
        for (int i = bid * 256 + tid; i < NBINS_PAD + 256; i += nb * 256)
            counts[i] = 0;
    }
    grid.sync();

    // ---- phase 1: prep (round-6 body, grid-stride over 4200 tiles) ----
    {
        float (*tile)[16][68] = (float (*)[16][68])(void*)smem;
        const int lq = lane & 3;
        const int lh = lane >> 2;
        for (int t = bid; t < 350 * (BB * NN); t += nb) {
            const int bn = t / 350;
            const int p0 = (t % 350) * 64;
            const int pw = p0 + 16 * wv;

            const float* fcam = feat + (size_t)bn * CCH * HWF;
            float4 f[4];
#pragma unroll
            for (int i = 0; i < 4; ++i)
                f[i] = *(const float4*)(fcam + (size_t)(16*i + lh) * HWF + pw + 4*lq);

            const float* dcam = depth + (size_t)bn * DDE * HWF;
            float4 mx;
            {
                float4 d0 = *(const float4*)(dcam + (size_t)(lh     ) * HWF + pw + 4*lq);
                float4 d1 = *(const float4*)(dcam + (size_t)(lh + 16) * HWF + pw + 4*lq);
                float4 d2 = *(const float4*)(dcam + (size_t)(lh + 32) * HWF + pw + 4*lq);
                float4 d3 = *(const float4*)(dcam + (size_t)(lh + 48) * HWF + pw + 4*lq);
                mx = f4max(f4max(d0, d1), f4max(d2, d3));
            }

#pragma unroll
            for (int i = 0; i < 4; ++i) {
                tile[wv][4*lq + 0][16*i + lh] = f[i].x;
                tile[wv][4*lq + 1][16*i + lh] = f[i].y;
                tile[wv][4*lq + 2][16*i + lh] = f[i].z;
                tile[wv][4*lq + 3][16*i + lh] = f[i].w;
            }

#pragma unroll
            for (int m = 4; m <= 32; m <<= 1) {
                mx.x = fmaxf(mx.x, __shfl_xor(mx.x, m));
                mx.y = fmaxf(mx.y, __shfl_xor(mx.y, m));
                mx.z = fmaxf(mx.z, __shfl_xor(mx.z, m));
                mx.w = fmaxf(mx.w, __shfl_xor(mx.w, m));
            }
            if (lh == 0)
                *(float4*)(conf + (size_t)bn * HWF + pw + 4*lq) = mx;

            __half* ocam = feat_t + (size_t)bn * HWF * CCH;
#pragma unroll
            for (int s = 0; s < 2; ++s) {
                const int row = 8*s + (lane >> 3);
                const int c0  = 8 * (lane & 7);
                float4 a = *(const float4*)(&tile[wv][row][c0]);
                float4 b = *(const float4*)(&tile[wv][row][c0 + 4]);
                uint4 u = pack8h(a, b);
                *(uint4*)(ocam + (size_t)(pw + row) * CCH + c0) = u;
            }

            if (wv == 0) {   // c00-bin histogram for the block's 64-px window
                Geo g = geo_compute(bn, p0 + lane, I_inv, E_inv, Vm);
                const int base = (bn / NN) * HWB;
                const int cell = g.valid ? base + g.c00 : -1;
                bool leader; int runlen, leadlane;
                run_info(cell, lane, leader, runlen, leadlane);
                if (leader) atomicAdd(&counts[cell], runlen);
            }
        }
    }
    grid.sync();

    // ---- phase 2a: scan1 (blocks 0..319) ----
    if (bid < NSCANB) {
        int* tmp = (int*)(void*)smem;
        const int i = bid * 256 + tid;
        int v = counts[i];
        tmp[tid] = v; __syncthreads();
        for (int off = 1; off < 256; off <<= 1) {
            int x = (tid >= off) ? tmp[tid - off] : 0;
            __syncthreads();
            tmp[tid] += x;
            __syncthreads();
        }
        offsets[i] = tmp[tid] - v;
        if (tid == 255) bsum[bid] = tmp[255];
    }
    grid.sync();

    // ---- phase 2b: scan3 (blocks 0..319) ----
    if (bid < NSCANB) {
        int* s = (int*)(void*)smem;
        int part = 0;
        for (int i = tid; i < bid; i += 256) part += bsum[i];
        s[tid] = part; __syncthreads();
        for (int off = 128; off > 0; off >>= 1) {
            if (tid < off) s[tid] += s[tid + off];
            __syncthreads();
        }
        const int i = bid * 256 + tid;
        int v = offsets[i] + s[0];
        offsets[i] = v;
        cursor[i]  = v;
    }
    grid.sync();

    // ---- phase 3: place (grid-stride over 1056 tiles of 256 px) ----
    {
        for (int t = bid; t < 88 * (BB * NN); t += nb) {
            const int bn = t / 88;
            const int p  = (t % 88) * 256 + tid;
            const int inb = (p < HWF);
            const int pp = inb ? p : HWF - 1;
            Geo g = geo_compute(bn, pp, I_inv, E_inv, Vm);
            const int valid = inb && g.valid;
            if (__ballot(valid) == 0ull) continue;
            const int base = (bn / NN) * HWB;
            const int bin  = valid ? base + g.c00 : -1;

            bool leader; int runlen, leadlane;
            run_info(bin, lane, leader, runlen, leadlane);
            int pos_leader = 0;
            if (leader) pos_leader = atomicAdd(&cursor[bin], runlen);
            int pos = __shfl(pos_leader, leadlane) + (lane - leadlane);
            if (valid) {
                const float cf = conf[(size_t)bn * HWF + pp];
                entries[pos] = make_uint4((unsigned)bin, (unsigned)(bn * HWF + pp),
                                          pack2w(g.w00 * cf, g.w10 * cf),
                                          pack2w(g.w01 * cf, g.w11 * cf));
            }
        }
    }
    grid.sync();

    // ---- phase 4: gather (grid-stride over 1050 chunk-groups; wave = chunk) ----
    {
        const int total = offsets[NBINS];
        const float inv = 1.0f / 65535.0f;
        for (int gb = bid; gb < NCHUNK1 / 4; gb += nb) {
            const int chunk = gb * 4 + wv;
            const int start = chunk * 64;
            if (start >= total) continue;
            const int m = min(64, total - start);

            float a00 = 0.f, a10 = 0.f, a01 = 0.f, a11 = 0.f;
            int j = 0;
            for (; j + 8 <= m; j += 8) {
                uint4 ent[8];
#pragma unroll
                for (int k = 0; k < 8; ++k) ent[k] = entries[start + j + k];
                const unsigned nextbin = (j + 8 < m) ? entries[start + j + 8].x : 0xFFFFFFFFu;
                float f[8];
#pragma unroll
                for (int k = 0; k < 8; ++k)
                    f[k] = __half2float(feat_t[(size_t)ent[k].y * CCH + lane]);
#pragma unroll
                for (int k = 0; k < 8; ++k) {
                    a00 = fmaf(f[k], (float)(ent[k].z & 0xffffu) * inv, a00);
                    a10 = fmaf(f[k], (float)(ent[k].z >> 16)     * inv, a10);
                    a01 = fmaf(f[k], (float)(ent[k].w & 0xffffu) * inv, a01);
                    a11 = fmaf(f[k], (float)(ent[k].w >> 16)     * inv, a11);
                    const unsigned nbn = (k < 7) ? ent[k + 1].x : nextbin;
                    if (ent[k].x != nbn) {
                        float* ab = acc + (size_t)ent[k].x * CCH + lane;
                        atomicAdd(ab,                     a00);
                        atomicAdd(ab + (size_t)1   * CCH, a10);
                        atomicAdd(ab + (size_t)200 * CCH, a01);
                        atomicAdd(ab + (size_t)201 * CCH, a11);
                        a00 = a10 = a01 = a11 = 0.f;
                    }
                }
            }
            for (; j < m; ++j) {
                uint4 e = entries[start + j];
                float fv = __half2float(feat_t[(size_t)e.y * CCH + lane]);
                a00 = fmaf(fv, (float)(e.z & 0xffffu) * inv, a00);
                a10 = fmaf(fv, (float)(e.z >> 16)     * inv, a10);
                a01 = fmaf(fv, (float)(e.w & 0xffffu) * inv, a01);
                a11 = fmaf(fv, (float)(e.w >> 16)     * inv, a11);
                const unsigned nbn = (j + 1 < m) ? entries[start + j + 1].x : 0xFFFFFFFFu;
                if (e.x != nbn) {
                    float* ab = acc + (size_t)e.x * CCH + lane;
                    atomicAdd(ab,                     a00);
                    atomicAdd(ab + (size_t)1   * CCH, a10);
                    atomicAdd(ab + (size_t)200 * CCH, a01);
                    atomicAdd(ab + (size_t)201 * CCH, a11);
                    a00 = a10 = a01 = a11 = 0.f;
                }
            }
        }
    }
    grid.sync();

    // ---- phase 5: finalize (grid-stride over 1250 tiles) ----
    {
        float (*tt)[66] = (float (*)[66])(void*)smem;
        const int cc = tid >> 2;
        const int q  = tid & 3;
        for (int t = bid; t < 2 * 625; t += nb) {
            const int b     = t / 625;
            const int cell0 = (t % 625) * 64;
            __syncthreads();   // WAR: previous iteration readers done
            const float* abase = acc + ((size_t)b * HWB + cell0) * CCH;
#pragma unroll
            for (int i = 0; i < 4; ++i) {
                const int cg = q + 4 * i;
                float4 f = *(const float4*)(abase + (size_t)cc * CCH + 4 * cg);
                tt[cc][4*cg+0] = f.x; tt[cc][4*cg+1] = f.y;
                tt[cc][4*cg+2] = f.z; tt[cc][4*cg+3] = f.w;
            }
            __syncthreads();
            float* obase = out + (size_t)b * CCH * HWB + cell0;
#pragma unroll
            for (int i = 0; i < 4; ++i) {
                const int lg = q + 4 * i;
                float4 o;
                o.x = tt[4*lg+0][cc] * (1.0f/6.0f);
                o.y = tt[4*lg+1][cc] * (1.0f/6.0f);
                o.z = tt[4*lg+2][cc] * (1.0f/6.0f);
                o.w = tt[4*lg+3][cc] * (1.0f/6.0f);
                *(float4*)(obase + (size_t)cc * HWB + 4 * lg) = o;
            }
        }
    }
}

// ====================== fallback pipeline (round-7, measured 254.7us) ======================
__global__ __launch_bounds__(256) void transpose_kernel(
    const float* __restrict__ feat, __half* __restrict__ feat_t)
{
    __shared__ float tile[4][16][68];
    const int bn   = blockIdx.y;
    const int p0   = blockIdx.x * 64;
    const int tid  = threadIdx.x;
    const int lane = tid & 63, wv = tid >> 6;
    const int lq   = lane & 3;
    const int lh   = lane >> 2;
    const int pw   = p0 + 16 * wv;

    const float* fcam = feat + (size_t)bn * CCH * HWF;
    float4 f[4];
#pragma unroll
    for (int i = 0; i < 4; ++i)
        f[i] = *(const float4*)(fcam + (size_t)(16*i + lh) * HWF + pw + 4*lq);
#pragma unroll
    for (int i = 0; i < 4; ++i) {
        tile[wv][4*lq + 0][16*i + lh] = f[i].x;
        tile[wv][4*lq + 1][16*i + lh] = f[i].y;
        tile[wv][4*lq + 2][16*i + lh] = f[i].z;
        tile[wv][4*lq + 3][16*i + lh] = f[i].w;
    }
    __half* ocam = feat_t + (size_t)bn * HWF * CCH;
#pragma unroll
    for (int s = 0; s < 2; ++s) {
        const int row = 8*s + (lane >> 3);
        const int c0  = 8 * (lane & 7);
        float4 a = *(const float4*)(&tile[wv][row][c0]);
        float4 b = *(const float4*)(&tile[wv][row][c0 + 4]);
        uint4 u = pack8h(a, b);
        *(uint4*)(ocam + (size_t)(pw + row) * CCH + c0) = u;
    }
}

__global__ __launch_bounds__(256) void conf_hist_kernel(
    const float* __restrict__ depth,
    const float* __restrict__ I_inv, const float* __restrict__ E_inv,
    const float* __restrict__ Vm,
    float* __restrict__ conf, int* __restrict__ counts)
{
    const int bn   = blockIdx.y;
    const int p0   = blockIdx.x * 128;
    const int tid  = threadIdx.x;
    const int lane = tid & 63, wv = tid >> 6;
    const int lq   = lane & 3;
    const int lh   = lane >> 2;
    const int pw   = p0 + 32 * wv;

    const float* dcam = depth + (size_t)bn * DDE * HWF;
    float4 d0[4], d1[4];
#pragma unroll
    for (int i = 0; i < 4; ++i)
        d0[i] = *(const float4*)(dcam + (size_t)(lh + 16*i) * HWF + pw + 4*lq);
#pragma unroll
    for (int i = 0; i < 4; ++i)
        d1[i] = *(const float4*)(dcam + (size_t)(lh + 16*i) * HWF + pw + 16 + 4*lq);

    float4 m0 = f4max(f4max(d0[0], d0[1]), f4max(d0[2], d0[3]));
    float4 m1 = f4max(f4max(d1[0], d1[1]), f4max(d1[2], d1[3]));
#pragma unroll
    for (int m = 4; m <= 32; m <<= 1) {
        m0.x = fmaxf(m0.x, __shfl_xor(m0.x, m));
        m0.y = fmaxf(m0.y, __shfl_xor(m0.y, m));
        m0.z = fmaxf(m0.z, __shfl_xor(m0.z, m));
        m0.w = fmaxf(m0.w, __shfl_xor(m0.w, m));
        m1.x = fmaxf(m1.x, __shfl_xor(m1.x, m));
        m1.y = fmaxf(m1.y, __shfl_xor(m1.y, m));
        m1.z = fmaxf(m1.z, __shfl_xor(m1.z, m));
        m1.w = fmaxf(m1.w, __shfl_xor(m1.w, m));
    }
    if (lh == 0) {
        *(float4*)(conf + (size_t)bn * HWF + pw + 4*lq)      = m0;
        *(float4*)(conf + (size_t)bn * HWF + pw + 16 + 4*lq) = m1;
    }
    {
        Geo g = geo_compute(bn, pw + (lane & 31), I_inv, E_inv, Vm);
        const int base = (bn / NN) * HWB;
        const int cell = ((lane < 32) && g.valid) ? base + g.c00 : -1;
        bool leader; int runlen, leadlane;
        run_info(cell, lane, leader, runlen, leadlane);
        if (leader) atomicAdd(&counts[cell], runlen);
    }
}

__global__ __launch_bounds__(256) void scan1_kernel(
    const int* __restrict__ counts, int* __restrict__ offsets, int* __restrict__ bsum)
{
    __shared__ int tmp[256];
    const int t = threadIdx.x;
    const int i = blockIdx.x * 256 + t;
    int v = counts[i];
    tmp[t] = v; __syncthreads();
    for (int off = 1; off < 256; off <<= 1) {
        int x = (t >= off) ? tmp[t - off] : 0;
        __syncthreads();
        tmp[t] += x;
        __syncthreads();
    }
    offsets[i] = tmp[t] - v;
    if (t == 255) bsum[blockIdx.x] = tmp[255];
}

__global__ __launch_bounds__(256) void scan3_kernel(
    int* __restrict__ offsets, const int* __restrict__ bsum, int* __restrict__ cursor)
{
    __shared__ int s[256];
    const int t = threadIdx.x;
    int part = 0;
    for (int i = t; i < blockIdx.x; i += 256) part += bsum[i];
    s[t] = part; __syncthreads();
    for (int off = 128; off > 0; off >>= 1) {
        if (t < off) s[t] += s[t + off];
        __syncthreads();
    }
    const int i = blockIdx.x * 256 + t;
    int v = offsets[i] + s[0];
    offsets[i] = v;
    cursor[i]  = v;
}

__global__ __launch_bounds__(256) void place_kernel(
    const float* __restrict__ conf,
    const float* __restrict__ I_inv, const float* __restrict__ E_inv,
    const float* __restrict__ Vm,
    int* __restrict__ cursor, uint4* __restrict__ entries)
{
    const int bn = blockIdx.y;
    const int p  = blockIdx.x * blockDim.x + threadIdx.x;
    const int lane = threadIdx.x & 63;
    const int inb = (p < HWF);
    const int pp = inb ? p : HWF - 1;
    Geo g = geo_compute(bn, pp, I_inv, E_inv, Vm);
    const int valid = inb && g.valid;
    if (__ballot(valid) == 0ull) return;
    const int base = (bn / NN) * HWB;
    const int bin  = valid ? base + g.c00 : -1;

    bool leader; int runlen, leadlane;
    run_info(bin, lane, leader, runlen, leadlane);
    int pos_leader = 0;
    if (leader) pos_leader = atomicAdd(&cursor[bin], runlen);
    int pos = __shfl(pos_leader, leadlane) + (lane - leadlane);
    if (valid) {
        const float cf = conf[(size_t)bn * HWF + pp];
        entries[pos] = make_uint4((unsigned)bin, (unsigned)(bn * HWF + pp),
                                  pack2w(g.w00 * cf, g.w10 * cf),
                                  pack2w(g.w01 * cf, g.w11 * cf));
    }
}

__global__ __launch_bounds__(256) void gather_seg_kernel(
    const uint4* __restrict__ entries, const int* __restrict__ total_ptr,
    const __half* __restrict__ feat_t, float* __restrict__ acc)
{
    const int lane = threadIdx.x & 63, wv = threadIdx.x >> 6;
    const int chunk = blockIdx.x * 4 + wv;
    const int total = *total_ptr;
    const int start = chunk * 64;
    if (start >= total) return;
    const int m = min(64, total - start);

    const float inv = 1.0f / 65535.0f;
    float a00 = 0.f, a10 = 0.f, a01 = 0.f, a11 = 0.f;
    int j = 0;
    for (; j + 8 <= m; j += 8) {
        uint4 ent[8];
#pragma unroll
        for (int k = 0; k < 8; ++k) ent[k] = entries[start + j + k];
        const unsigned nextbin = (j + 8 < m) ? entries[start + j + 8].x : 0xFFFFFFFFu;
        float f[8];
#pragma unroll
        for (int k = 0; k < 8; ++k)
            f[k] = __half2float(feat_t[(size_t)ent[k].y * CCH + lane]);
#pragma unroll
        for (int k = 0; k < 8; ++k) {
            a00 = fmaf(f[k], (float)(ent[k].z & 0xffffu) * inv, a00);
            a10 = fmaf(f[k], (float)(ent[k].z >> 16)     * inv, a10);
            a01 = fmaf(f[k], (float)(ent[k].w & 0xffffu) * inv, a01);
            a11 = fmaf(f[k], (float)(ent[k].w >> 16)     * inv, a11);
            const unsigned nbn = (k < 7) ? ent[k + 1].x : nextbin;
            if (ent[k].x != nbn) {
                float* ab = acc + (size_t)ent[k].x * CCH + lane;
                atomicAdd(ab,                     a00);
                atomicAdd(ab + (size_t)1   * CCH, a10);
                atomicAdd(ab + (size_t)200 * CCH, a01);
                atomicAdd(ab + (size_t)201 * CCH, a11);
                a00 = a10 = a01 = a11 = 0.f;
            }
        }
    }
    for (; j < m; ++j) {
        uint4 e = entries[start + j];
        float fv = __half2float(feat_t[(size_t)e.y * CCH + lane]);
        a00 = fmaf(fv, (float)(e.z & 0xffffu) * inv, a00);
        a10 = fmaf(fv, (float)(e.z >> 16)     * inv, a10);
        a01 = fmaf(fv, (float)(e.w & 0xffffu) * inv, a01);
        a11 = fmaf(fv, (float)(e.w >> 16)     * inv, a11);
        const unsigned nbn = (j + 1 < m) ? entries[start + j + 1].x : 0xFFFFFFFFu;
        if (e.x != nbn) {
            float* ab = acc + (size_t)e.x * CCH + lane;
            atomicAdd(ab,                     a00);
            atomicAdd(ab + (size_t)1   * CCH, a10);
            atomicAdd(ab + (size_t)200 * CCH, a01);
            atomicAdd(ab + (size_t)201 * CCH, a11);
            a00 = a10 = a01 = a11 = 0.f;
        }
    }
}

__global__ __launch_bounds__(256) void finalize_kernel(
    const float* __restrict__ acc, float* __restrict__ out)
{
    __shared__ float t[64][66];
    const int b     = blockIdx.y;
    const int cell0 = blockIdx.x * 64;
    const int cc    = threadIdx.x >> 2;
    const int q     = threadIdx.x & 3;

    const float* abase = acc + ((size_t)b * HWB + cell0) * CCH;
#pragma unroll
    for (int i = 0; i < 4; ++i) {
        const int cg = q + 4 * i;
        float4 f = *(const float4*)(abase + (size_t)cc * CCH + 4 * cg);
        t[cc][4*cg+0] = f.x; t[cc][4*cg+1] = f.y;
        t[cc][4*cg+2] = f.z; t[cc][4*cg+3] = f.w;
    }
    __syncthreads();
    float* obase = out + (size_t)b * CCH * HWB + cell0;
#pragma unroll
    for (int i = 0; i < 4; ++i) {
        const int lg = q + 4 * i;
        float4 o;
        o.x = t[4*lg+0][cc] * (1.0f/6.0f);
        o.y = t[4*lg+1][cc] * (1.0f/6.0f);
        o.z = t[4*lg+2][cc] * (1.0f/6.0f);
        o.w = t[4*lg+3][cc] * (1.0f/6.0f);
        *(float4*)(obase + (size_t)cc * HWB + 4 * lg) = o;
    }
}

extern "C" void kernel_launch(void* const* d_in, const int* in_sizes, int n_in,
                              void* d_out, int out_size, void* d_ws, size_t ws_size,
                              hipStream_t stream) {
    const float* feat  = (const float*)d_in[0];
    const float* depth = (const float*)d_in[1];
    const float* I_inv = (const float*)d_in[2];
    const float* E_inv = (const float*)d_in[3];
    const float* Vm    = (const float*)d_in[4];
    float* out = (float*)d_out;

    size_t off = 0;
    char* wsb = (char*)d_ws;
    auto carve = [&](size_t bytes) -> void* {
        void* p = wsb + off; off += (bytes + 255) & ~(size_t)255; return p;
    };
    __half* feat_t = (__half*)carve((size_t)BB * NN * CCH * HWF * 2); // 34.4 MB fp16
    float* acc     = (float*)carve(ACC_ELEMS * 4);                    // 20.5 MB
    int*   counts  = (int*)  carve((NBINS_PAD + 256) * 4);            // 0.33 MB
    uint4* entries = (uint4*)carve((size_t)MAXENT1 * 16);             //  4.3 MB
    float* conf    = (float*)carve((size_t)BB * NN * HWF * 4);        //  1.1 MB
    int*   offsets = (int*)  carve((NBINS_PAD + 256) * 4);
    int*   cursor  = (int*)  carve((NBINS_PAD + 256) * 4);
    int*   bsum    = (int*)  carve(NSCANB * 4);
    (void)ws_size;

    // one-time cooperative capability + co-residency query (host-side, allowed calls)
    static int s_grid = -2;   // -2 = uninitialized, 0 = cooperative unusable
    if (s_grid == -2) {
        int dev = 0;
        hipGetDevice(&dev);
        hipDeviceProp_t prop;
        if (hipGetDeviceProperties(&prop, dev) == hipSuccess && prop.cooperativeLaunch) {
            int maxb = 0;
            if (hipOccupancyMaxActiveBlocksPerMultiprocessor(&maxb, mega_kernel, 256, 0)
                    == hipSuccess && maxb > 0) {
                long g = (long)maxb * prop.multiProcessorCount;
                if (g > 2048) g = 2048;
                s_grid = (int)g;
            } else s_grid = 0;
        } else s_grid = 0;
    }

    bool done = false;
    if (s_grid >= 64) {
        void* kargs[14] = {
            (void*)&feat, (void*)&depth, (void*)&I_inv, (void*)&E_inv, (void*)&Vm,
            (void*)&feat_t, (void*)&conf, (void*)&counts, (void*)&offsets,
            (void*)&cursor, (void*)&bsum, (void*)&entries, (void*)&acc, (void*)&out
        };
        hipError_t err = hipLaunchCooperativeKernel(mega_kernel,
                                                    dim3((unsigned)s_grid), dim3(256),
                                                    kargs, 0, stream);
        if (err == hipSuccess) done = true;
        else s_grid = 0;   // never retry cooperative in this process
    }

    if (!done) {
        // fallback: round-7 multi-kernel pipeline (measured 254.7 us)
        hipMemsetAsync(acc, 0, ACC_ELEMS * 4 + (NBINS_PAD + 256) * 4, stream);

        dim3 tgrid(HWF / 64, BB * NN);                 // (350,12)
        transpose_kernel<<<tgrid, 256, 0, stream>>>(feat, feat_t);

        dim3 cgrid(HWF / 128, BB * NN);                // (175,12)
        conf_hist_kernel<<<cgrid, 256, 0, stream>>>(depth, I_inv, E_inv, Vm,
                                                    conf, counts);

        scan1_kernel<<<NSCANB, 256, 0, stream>>>(counts, offsets, bsum);
        scan3_kernel<<<NSCANB, 256, 0, stream>>>(offsets, bsum, cursor);

        dim3 plgrid((HWF + 255) / 256, BB * NN);       // (88,12)
        place_kernel<<<plgrid, 256, 0, stream>>>(conf, I_inv, E_inv, Vm,
                                                 cursor, entries);

        gather_seg_kernel<<<NCHUNK1 / 4, 256, 0, stream>>>(
            entries, offsets + NBINS, feat_t, acc);

        dim3 fgrid(HWB / 64, BB);                      // (625,2)
        finalize_kernel<<<fgrid, 256, 0, stream>>>(acc, out);
    }
}

// Round 10
// 261.057 us; speedup vs baseline: 2.7144x; 2.7144x over previous
//
#include <hip/hip_runtime.h>
#include <hip/hip_fp16.h>

// LiftSplatBEV: B=2, N=6, C=64, HF=112, WF=200, D=64, BEV 200x200
#define BB   2
#define NN   6
#define CCH  64
#define HFE  112
#define WFE  200
#define DDE  64
#define HWF  (HFE*WFE)      // 22400 feature pixels (= 350*64)
#define BEVH 200
#define BEVW 200
#define HWB  (BEVH*BEVW)    // 40000 BEV cells
#define NBINS (BB*HWB)      // 80000 (b,cell) bins
#define NBINS_PAD 81920     // 320*256
#define NSCANB (NBINS_PAD/256)  // 320
#define NPIX   (BB*NN*HWF)      // 268,800 pixels (= max entries, ONE per valid pixel)
#define NCHUNK1 (NPIX/64)       // 4200 64-entry chunks
#define ACC_ELEMS ((size_t)BB*HWB*CCH)   // channel-last [b*HWB+cell][c]

__device__ __forceinline__ float4 f4max(float4 a, float4 b) {
    return make_float4(fmaxf(a.x,b.x), fmaxf(a.y,b.y), fmaxf(a.z,b.z), fmaxf(a.w,b.w));
}

// pack 8 floats -> 8 halves (16B)
__device__ __forceinline__ uint4 pack8h(float4 a, float4 b) {
    __half2 h0 = __float22half2_rn(make_float2(a.x, a.y));
    __half2 h1 = __float22half2_rn(make_float2(a.z, a.w));
    __half2 h2 = __float22half2_rn(make_float2(b.x, b.y));
    __half2 h3 = __float22half2_rn(make_float2(b.z, b.w));
    uint4 u;
    u.x = *(unsigned*)&h0; u.y = *(unsigned*)&h1;
    u.z = *(unsigned*)&h2; u.w = *(unsigned*)&h3;
    return u;
}

// ---------------- shared geometry (bug-faithful to reference) ----------------
struct Geo {
    int valid;
    int c00;
    float w00, w10, w01, w11;
};

__device__ __forceinline__ Geo geo_compute(int bn, int p,
    const float* __restrict__ I_inv, const float* __restrict__ E_inv,
    const float* __restrict__ Vm)
{
    Geo g; g.valid = 0; g.c00 = -1;
    g.w00 = g.w10 = g.w01 = g.w11 = 0.f;
    // bug-faithful w-outer flatten: u = p/112, v = p%112
    const float u = (float)(p / HFE);
    const float v = (float)(p % HFE);
    const float* Ii = I_inv + bn * 9;
    const float* Ei = E_inv + bn * 16;
    float cx = Ii[0]*u + Ii[1]*v + Ii[2];
    float cy = Ii[3]*u + Ii[4]*v + Ii[5];
    float cz = Ii[6]*u + Ii[7]*v + Ii[8];
    float tx = Ei[3], ty = Ei[7], tz = Ei[11];
    float dx = Ei[0]*cx + Ei[1]*cy + Ei[2] *cz + tx;   // includes translation (bug-faithful)
    float dy = Ei[4]*cx + Ei[5]*cy + Ei[6] *cz + ty;
    float dz = Ei[8]*cx + Ei[9]*cy + Ei[10]*cz + tz;
    float s  = -tz / fmaxf(dz, 1e-6f);
    float ex = tx + dx * s;
    float ey = ty + dy * s;
    float prx = Vm[0]*ex + Vm[1]*ey + Vm[2];
    float pry = Vm[3]*ex + Vm[4]*ey + Vm[5];
    float prz = Vm[6]*ex + Vm[7]*ey + Vm[8];
    float den = fmaxf(prz, 1e-7f);
    float bx = prx / den, by = pry / den;
    // bug-faithful gx->px roundtrip, same association order as reference
    float gx = bx / (float)(BEVW-1) * 2.0f - 1.0f;
    float gy = by / (float)(BEVH-1) * 2.0f - 1.0f;
    float px = (gx + 1.0f) * (float)(BEVW-1) / 2.0f;
    float py = (gy + 1.0f) * (float)(BEVH-1) / 2.0f;
    float x0f = fminf(fmaxf(floorf(px), 0.0f), (float)(BEVW-1));
    float y0f = fminf(fmaxf(floorf(py), 0.0f), (float)(BEVH-1));
    float x1f = fminf(x0f + 1.0f, (float)(BEVW-1));
    float y1f = fminf(y0f + 1.0f, (float)(BEVH-1));
    // far-edge-degenerate slots cancel exactly in the fp64 np reference: skip
    if (x0f == x1f || y0f == y1f) return g;
    float wx0 = x1f - px, wx1 = px - x0f;
    float wy0 = y1f - py, wy1 = py - y0f;
    int x0 = (int)x0f, y0 = (int)y0f;
    g.c00 = y0*BEVW + x0;
    g.w00 = wx0*wy0;  g.w10 = wx1*wy0;
    g.w01 = wx0*wy1;  g.w11 = wx1*wy1;
    // for valid pixels x1=x0+1, y1=y0+1 => corners = c00 + {0,1,200,201}
    g.valid = 1;
    return g;
}

// Wave-run aggregation: consecutive lanes holding the same cell form a run.
__device__ __forceinline__ void run_info(int cell, int lane,
                                         bool& leader, int& runlen, int& leadlane)
{
    int prev = __shfl_up(cell, 1);
    bool change = (lane == 0) || (cell != prev);
    unsigned long long bal = __ballot(change);
    unsigned long long below = bal & (~0ull >> (63 - lane));
    leadlane = 63 - __builtin_clzll(below);
    unsigned long long above = (lane == 63) ? 0ull : (bal >> (lane + 1));
    int next = (above == 0ull) ? 64 : (lane + 1 + __builtin_ffsll((long long)above) - 1);
    runlen = next - lane;
    leader = change && (cell >= 0);
}

__device__ __forceinline__ unsigned pack2w(float a, float b) {
    unsigned ua = __float2uint_rn(a * 65535.0f);
    unsigned ub = __float2uint_rn(b * 65535.0f);
    return ua | (ub << 16);
}

// ---------------- prep v6: transpose fp16 + conf + geo + pixel-order entries + hist ----
// Grid (350,12), block 256 (4 waves), 16 px/wave, barrier-free (same-wave LDS handoffs
// only). vs round-6 measured 60us body: conf global store replaced by a same-wave LDS
// handoff feeding the FULL entry payload pent[px] = {bin, px, w00w10*conf, w01w11*conf}
// in pixel order. Geo runs once per pixel TOTAL (per-wave for its own 16 px); the
// c00 histogram is per-wave (runs split at 16-px boundaries; per-bin counts identical).
__global__ __launch_bounds__(256) void prep_kernel(
    const float* __restrict__ feat,    // [12,64,22400]
    const float* __restrict__ depth,   // [12,64,22400]
    const float* __restrict__ I_inv, const float* __restrict__ E_inv,
    const float* __restrict__ Vm,
    __half* __restrict__ feat_t,       // [12,22400,64] fp16
    uint4* __restrict__ pent,          // [NPIX] pixel-order entry payloads
    int* __restrict__ counts)          // [NBINS_PAD]
{
    __shared__ float tile[4][16][68];  // per-wave private 16px x 64ch tile
    __shared__ float confc[4][16];     // per-wave conf handoff (px = pw + idx)

    const int bn   = blockIdx.y;
    const int p0   = blockIdx.x * 64;          // 22400 = 350*64
    const int tid  = threadIdx.x;
    const int lane = tid & 63, wv = tid >> 6;
    const int lq   = lane & 3;
    const int lh   = lane >> 2;
    const int pw   = p0 + 16 * wv;

    // ---- feat transpose loads
    const float* fcam = feat + (size_t)bn * CCH * HWF;
    float4 f[4];
#pragma unroll
    for (int i = 0; i < 4; ++i)
        f[i] = *(const float4*)(fcam + (size_t)(16*i + lh) * HWF + pw + 4*lq);

    // ---- depth-max loads
    const float* dcam = depth + (size_t)bn * DDE * HWF;
    float4 mx;
    {
        float4 d0 = *(const float4*)(dcam + (size_t)(lh     ) * HWF + pw + 4*lq);
        float4 d1 = *(const float4*)(dcam + (size_t)(lh + 16) * HWF + pw + 4*lq);
        float4 d2 = *(const float4*)(dcam + (size_t)(lh + 32) * HWF + pw + 4*lq);
        float4 d3 = *(const float4*)(dcam + (size_t)(lh + 48) * HWF + pw + 4*lq);
        mx = f4max(f4max(d0, d1), f4max(d2, d3));
    }

    // ---- LDS transpose write (2-way bank alias, free)
#pragma unroll
    for (int i = 0; i < 4; ++i) {
        tile[wv][4*lq + 0][16*i + lh] = f[i].x;
        tile[wv][4*lq + 1][16*i + lh] = f[i].y;
        tile[wv][4*lq + 2][16*i + lh] = f[i].z;
        tile[wv][4*lq + 3][16*i + lh] = f[i].w;
    }

    // ---- conf reduce over the 16 lanes sharing lq; lh==0 lanes hand off via LDS
#pragma unroll
    for (int m = 4; m <= 32; m <<= 1) {
        mx.x = fmaxf(mx.x, __shfl_xor(mx.x, m));
        mx.y = fmaxf(mx.y, __shfl_xor(mx.y, m));
        mx.z = fmaxf(mx.z, __shfl_xor(mx.z, m));
        mx.w = fmaxf(mx.w, __shfl_xor(mx.w, m));
    }
    if (lh == 0)
        *(float4*)(&confc[wv][4*lq]) = mx;   // conf for px pw+4lq..+3

    // ---- feat_t fp16 store (2x 16B/lane, fully contiguous 1KB per instruction)
    __half* ocam = feat_t + (size_t)bn * HWF * CCH;
#pragma unroll
    for (int s = 0; s < 2; ++s) {
        const int row = 8*s + (lane >> 3);
        const int c0  = 8 * (lane & 7);
        float4 a = *(const float4*)(&tile[wv][row][c0]);
        float4 b = *(const float4*)(&tile[wv][row][c0 + 4]);
        uint4 u = pack8h(a, b);
        *(uint4*)(ocam + (size_t)(pw + row) * CCH + c0) = u;
    }

    // ---- geo + pixel-order entry + histogram (per-wave, lanes 0..15 carry real px)
    {
        const int li = lane & 15;
        Geo g = geo_compute(bn, pw + li, I_inv, E_inv, Vm);
        const int base = (bn / NN) * HWB;
        const int bin  = ((lane < 16) && g.valid) ? base + g.c00 : -1;

        if (lane < 16) {
            const float cf = confc[wv][li];         // same-wave LDS -> lgkmcnt only
            pent[(size_t)bn * HWF + pw + lane] =
                make_uint4((unsigned)bin, (unsigned)(bn * HWF + pw + lane),
                           pack2w(g.w00 * cf, g.w10 * cf),
                           pack2w(g.w01 * cf, g.w11 * cf));
        }
        bool leader; int runlen, leadlane;
        run_info(bin, lane, leader, runlen, leadlane);
        if (leader) atomicAdd(&counts[bin], runlen);
    }
}

// ---------------- single-pass scan: local scan + decoupled aggregate publish ----------
// 320 blocks (all co-resident: tiny LDS/VGPR). Block bid scans its 256 counts,
// publishes its aggregate via device-scope atomics (agg+flag), then sums all
// predecessors' aggregates (spin until published). Idle time zeroes acc.
__global__ __launch_bounds__(256) void scan_kernel(
    const int* __restrict__ counts, int* __restrict__ offsets, int* __restrict__ cursor,
    int* __restrict__ agg, int* __restrict__ flag, float* __restrict__ acc)
{
    __shared__ int tmp[256];
    const int t = threadIdx.x;
    const int bid = blockIdx.x;
    const int i = bid * 256 + t;

    int v = counts[i];
    tmp[t] = v; __syncthreads();
    for (int off = 1; off < 256; off <<= 1) {
        int x = (t >= off) ? tmp[t - off] : 0;
        __syncthreads();
        tmp[t] += x;
        __syncthreads();
    }
    const int excl = tmp[t] - v;
    if (t == 255) {
        atomicExch(&agg[bid], tmp[255]);
        __threadfence();
        atomicExch(&flag[bid], 1);
    }
    __syncthreads();          // everyone done reading tmp before reuse

    // exclusive prefix over predecessor blocks (device-scope atomic reads)
    int part = 0;
    for (int j = t; j < bid; j += 256) {
        while (atomicAdd(&flag[j], 0) == 0) __builtin_amdgcn_s_sleep(8);
        part += atomicAdd(&agg[j], 0);
    }
    tmp[t] = part; __syncthreads();
    for (int off = 128; off > 0; off >>= 1) {
        if (t < off) tmp[t] += tmp[t + off];
        __syncthreads();
    }
    const int v2 = excl + tmp[0];
    offsets[i] = v2;
    cursor[i]  = v2;

    // zero acc (stream-ordered before gather)
    float4* a4 = (float4*)acc;
    const int n4 = (int)(ACC_ELEMS / 4);
    for (int k = bid * 256 + t; k < n4; k += NSCANB * 256)
        a4[k] = make_float4(0.f, 0.f, 0.f, 0.f);
}

// ---------------- scatter: pixel-order pent -> bin-sorted entries (no geo, no conf) ---
__global__ __launch_bounds__(256) void scatter_kernel(
    const uint4* __restrict__ pent, int* __restrict__ cursor,
    uint4* __restrict__ entries)
{
    const int idx  = blockIdx.x * 256 + threadIdx.x;   // NPIX = 1050*256 exactly
    const int lane = threadIdx.x & 63;
    uint4 e = pent[idx];
    const int bin = (int)e.x;
    if (__ballot(bin >= 0) == 0ull) return;

    bool leader; int runlen, leadlane;
    run_info(bin, lane, leader, runlen, leadlane);
    int pos_leader = 0;
    if (leader) pos_leader = atomicAdd(&cursor[bin], runlen);
    int pos = __shfl(pos_leader, leadlane) + (lane - leadlane);
    if (bin >= 0) entries[pos] = e;
}

// ---------------- gather: wave = 64-entry chunk, lane = channel (round-7 body) --------
__global__ __launch_bounds__(256) void gather_seg_kernel(
    const uint4* __restrict__ entries, const int* __restrict__ total_ptr,
    const __half* __restrict__ feat_t, float* __restrict__ acc)
{
    const int lane = threadIdx.x & 63, wv = threadIdx.x >> 6;
    const int chunk = blockIdx.x * 4 + wv;
    const int total = *total_ptr;
    const int start = chunk * 64;
    if (start >= total) return;
    const int m = min(64, total - start);

    const float inv = 1.0f / 65535.0f;
    float a00 = 0.f, a10 = 0.f, a01 = 0.f, a11 = 0.f;
    int j = 0;
    for (; j + 8 <= m; j += 8) {
        uint4 ent[8];
#pragma unroll
        for (int k = 0; k < 8; ++k) ent[k] = entries[start + j + k];   // wave-uniform
        const unsigned nextbin = (j + 8 < m) ? entries[start + j + 8].x : 0xFFFFFFFFu;
        float f[8];
#pragma unroll
        for (int k = 0; k < 8; ++k)
            f[k] = __half2float(feat_t[(size_t)ent[k].y * CCH + lane]);
#pragma unroll
        for (int k = 0; k < 8; ++k) {
            a00 = fmaf(f[k], (float)(ent[k].z & 0xffffu) * inv, a00);
            a10 = fmaf(f[k], (float)(ent[k].z >> 16)     * inv, a10);
            a01 = fmaf(f[k], (float)(ent[k].w & 0xffffu) * inv, a01);
            a11 = fmaf(f[k], (float)(ent[k].w >> 16)     * inv, a11);
            const unsigned nbn = (k < 7) ? ent[k + 1].x : nextbin;
            if (ent[k].x != nbn) {
                float* ab = acc + (size_t)ent[k].x * CCH + lane;
                atomicAdd(ab,                     a00);
                atomicAdd(ab + (size_t)1   * CCH, a10);
                atomicAdd(ab + (size_t)200 * CCH, a01);
                atomicAdd(ab + (size_t)201 * CCH, a11);
                a00 = a10 = a01 = a11 = 0.f;
            }
        }
    }
    for (; j < m; ++j) {
        uint4 e = entries[start + j];
        float fv = __half2float(feat_t[(size_t)e.y * CCH + lane]);
        a00 = fmaf(fv, (float)(e.z & 0xffffu) * inv, a00);
        a10 = fmaf(fv, (float)(e.z >> 16)     * inv, a10);
        a01 = fmaf(fv, (float)(e.w & 0xffffu) * inv, a01);
        a11 = fmaf(fv, (float)(e.w >> 16)     * inv, a11);
        const unsigned nbn = (j + 1 < m) ? entries[start + j + 1].x : 0xFFFFFFFFu;
        if (e.x != nbn) {
            float* ab = acc + (size_t)e.x * CCH + lane;
            atomicAdd(ab,                     a00);
            atomicAdd(ab + (size_t)1   * CCH, a10);
            atomicAdd(ab + (size_t)200 * CCH, a01);
            atomicAdd(ab + (size_t)201 * CCH, a11);
            a00 = a10 = a01 = a11 = 0.f;
        }
    }
}

// ---------------- finalize: out[b][c][cell] = acc[b*HWB+cell][c] / 6 ------------------
__global__ __launch_bounds__(256) void finalize_kernel(
    const float* __restrict__ acc, float* __restrict__ out)
{
    __shared__ float t[64][66];
    const int b     = blockIdx.y;
    const int cell0 = blockIdx.x * 64;
    const int cc    = threadIdx.x >> 2;
    const int q     = threadIdx.x & 3;

    const float* abase = acc + ((size_t)b * HWB + cell0) * CCH;
#pragma unroll
    for (int i = 0; i < 4; ++i) {
        const int cg = q + 4 * i;
        float4 f = *(const float4*)(abase + (size_t)cc * CCH + 4 * cg);
        t[cc][4*cg+0] = f.x; t[cc][4*cg+1] = f.y;
        t[cc][4*cg+2] = f.z; t[cc][4*cg+3] = f.w;
    }
    __syncthreads();
    float* obase = out + (size_t)b * CCH * HWB + cell0;
#pragma unroll
    for (int i = 0; i < 4; ++i) {
        const int lg = q + 4 * i;
        float4 o;
        o.x = t[4*lg+0][cc] * (1.0f/6.0f);
        o.y = t[4*lg+1][cc] * (1.0f/6.0f);
        o.z = t[4*lg+2][cc] * (1.0f/6.0f);
        o.w = t[4*lg+3][cc] * (1.0f/6.0f);
        *(float4*)(obase + (size_t)cc * HWB + 4 * lg) = o;
    }
}

extern "C" void kernel_launch(void* const* d_in, const int* in_sizes, int n_in,
                              void* d_out, int out_size, void* d_ws, size_t ws_size,
                              hipStream_t stream) {
    const float* feat  = (const float*)d_in[0];
    const float* depth = (const float*)d_in[1];
    const float* I_inv = (const float*)d_in[2];
    const float* E_inv = (const float*)d_in[3];
    const float* Vm    = (const float*)d_in[4];
    float* out = (float*)d_out;

    size_t off = 0;
    char* wsb = (char*)d_ws;
    auto carve = [&](size_t bytes) -> void* {
        void* p = wsb + off; off += (bytes + 255) & ~(size_t)255; return p;
    };
    __half* feat_t = (__half*)carve((size_t)BB * NN * CCH * HWF * 2); // 34.4 MB fp16
    float* acc     = (float*)carve(ACC_ELEMS * 4);                    // 20.5 MB (zeroed in scan)
    // counts + flag adjacent -> single small memset (0.34 MB)
    int*   counts  = (int*)  carve((size_t)NBINS_PAD * 4);
    int*   flag    = (int*)  carve((size_t)NSCANB * 4);
    int*   agg     = (int*)  carve((size_t)NSCANB * 4);               // no zero needed
    uint4* pent    = (uint4*)carve((size_t)NPIX * 16);                //  4.3 MB
    uint4* entries = (uint4*)carve((size_t)NPIX * 16);                //  4.3 MB
    int*   offsets = (int*)  carve((size_t)(NBINS_PAD + 256) * 4);
    int*   cursor  = (int*)  carve((size_t)(NBINS_PAD + 256) * 4);
    (void)ws_size;

    // counts and flag are contiguous (carve pads to 256B; NBINS_PAD*4 is 256B-aligned)
    hipMemsetAsync(counts, 0, (size_t)NBINS_PAD * 4 + 256, stream);

    dim3 pgrid(HWF / 64, BB * NN);                 // (350,12)
    prep_kernel<<<pgrid, 256, 0, stream>>>(feat, depth, I_inv, E_inv, Vm,
                                           feat_t, pent, counts);

    scan_kernel<<<NSCANB, 256, 0, stream>>>(counts, offsets, cursor, agg, flag, acc);

    scatter_kernel<<<NPIX / 256, 256, 0, stream>>>(pent, cursor, entries);  // 1050 blocks

    gather_seg_kernel<<<NCHUNK1 / 4, 256, 0, stream>>>(
        entries, offsets + NBINS, feat_t, acc);

    dim3 fgrid(HWB / 64, BB);                      // (625,2)
    finalize_kernel<<<fgrid, 256, 0, stream>>>(acc, out);
}